// Round 1
// baseline (296.129 us; speedup 1.0000x reference)
//
#include <hip/hip_runtime.h>
#include <hip/hip_bf16.h>

typedef __attribute__((ext_vector_type(8))) short short8;
typedef __attribute__((ext_vector_type(4))) float f32x4;

static constexpr int DM = 1024;   // d_model
static constexpr int NH = 16;     // heads
static constexpr int DK = 64;     // head dim
static constexpr int SL = 2048;   // seq len
static constexpr int BB = 4;      // batch
static constexpr size_t QKV_ELEMS = (size_t)BB * NH * SL * DK;  // 8388608
static constexpr float NEG_BIG = -30000.0f;          // exp2 -> 0
static constexpr float SC_LOG2E = 0.125f * 1.44269504088896340736f; // /sqrt(64)*log2(e)

union PackB { __hip_bfloat16 h[8]; uint4 u; };
union Pack4 { __hip_bfloat16 h[4]; uint2 u; };

// async global->LDS, 16 B per lane (dest = wave-uniform base + lane*16)
typedef __attribute__((address_space(1))) unsigned int gu32;
typedef __attribute__((address_space(3))) unsigned int lu32;
__device__ __forceinline__ void async_copy16(const void* g, void* l) {
    __builtin_amdgcn_global_load_lds((gu32*)g, (lu32*)l, 16, 0, 0);
}

// ---------------------------------------------------------------------------
// Bulk fp32 -> bf16 convert: x (8M elems) then Wq,Wk,Wv,Wo (1M each) into one
// contiguous bf16 region. One float4 per thread.
// ---------------------------------------------------------------------------
__global__ __launch_bounds__(256)
void cvt_all(const float* __restrict__ x,
             const float* __restrict__ wq, const float* __restrict__ wk,
             const float* __restrict__ wv, const float* __restrict__ wo,
             __hip_bfloat16* __restrict__ dst)
{
    const size_t i = (size_t)blockIdx.x * 256 + threadIdx.x;  // float4 index
    const float* src; size_t local;
    if (i < 2097152) { src = x; local = i; }
    else {
        const size_t j = i - 2097152;
        const int r = (int)(j >> 18);           // 262144 float4 per W
        local = j & 262143;
        src = (r == 0) ? wq : (r == 1) ? wk : (r == 2) ? wv : wo;
    }
    float4 f = reinterpret_cast<const float4*>(src)[local];
    Pack4 p;
    p.h[0] = __float2bfloat16(f.x); p.h[1] = __float2bfloat16(f.y);
    p.h[2] = __float2bfloat16(f.z); p.h[3] = __float2bfloat16(f.w);
    reinterpret_cast<uint2*>(dst)[i] = p.u;
}

// ---------------------------------------------------------------------------
// Fused QKV projection, BK=64 single-buffered: A (8192 x 1024 bf16) @ Wqkv^T.
// 16 barrier pairs (was 32), 32 MFMA per drain (was 16).
// LDS row stride = 128 B -> 16-way bank conflict if linear, so:
//   - LDS dest stays linear (global_load_lds constraint, rule #21),
//   - the per-lane GLOBAL source chunk is pre-swizzled: c = (lane&7)^(lane>>3),
//   - ds_read uses slot = (ks*4+quad)^(ln&7)  (bijective per 8-row stripe,
//     8 lanes/16B-slot = the 8-cycle b128 service floor).
// ---------------------------------------------------------------------------
__global__ __launch_bounds__(256)
void gemm_qkv(const __hip_bfloat16* __restrict__ A,
              const __hip_bfloat16* __restrict__ W,
              __hip_bfloat16* __restrict__ q_out,
              __hip_bfloat16* __restrict__ k_out,
              __hip_bfloat16* __restrict__ v_out)
{
    __shared__ __hip_bfloat16 As[128 * 64];   // contiguous: global_load_lds order
    __shared__ __hip_bfloat16 Bs[128 * 64];
    const int tid  = threadIdx.x;
    const int m0   = blockIdx.x * 128;
    const int n0   = blockIdx.y * 128;
    const int w    = tid >> 6;
    const int lane = tid & 63;
    const int quad = lane >> 4;
    const int ln   = lane & 15;
    const int wm   = (w & 1) * 64;
    const int wn   = (w >> 1) * 64;
    const int srow = lane >> 3;                    // 0..7
    const int sch  = ((lane & 7) ^ srow) * 8;      // swizzled source chunk

    f32x4 acc[4][4] = {};

    for (int k0 = 0; k0 < DM; k0 += 64) {
        #pragma unroll
        for (int j = 0; j < 4; j++) {
            const int rbase = w * 32 + j * 8;      // multiple of 8: stripe-aligned
            async_copy16(A + (size_t)(m0 + rbase + srow) * DM + k0 + sch,
                         &As[rbase * 64]);
            async_copy16(W + (size_t)(n0 + rbase + srow) * DM + k0 + sch,
                         &Bs[rbase * 64]);
        }
        __syncthreads();

        #pragma unroll
        for (int ks = 0; ks < 2; ks++) {
            short8 a[4], b[4];
            #pragma unroll
            for (int i = 0; i < 4; i++)
                a[i] = *reinterpret_cast<const short8*>(
                    &As[(wm + i*16 + ln) * 64 + (((ks*4 + quad) ^ (ln & 7)) * 8)]);
            #pragma unroll
            for (int j = 0; j < 4; j++)
                b[j] = *reinterpret_cast<const short8*>(
                    &Bs[(wn + j*16 + ln) * 64 + (((ks*4 + quad) ^ (ln & 7)) * 8)]);
            #pragma unroll
            for (int i = 0; i < 4; i++)
                #pragma unroll
                for (int j = 0; j < 4; j++)
                    acc[i][j] = __builtin_amdgcn_mfma_f32_16x16x32_bf16(a[i], b[j], acc[i][j], 0, 0, 0);
        }
        __syncthreads();
    }

    // Epilogue: C/D layout col=lane&15, row=quad*4+reg  [m89/m91]
    #pragma unroll
    for (int i = 0; i < 4; i++) {
        #pragma unroll
        for (int j = 0; j < 4; j++) {
            #pragma unroll
            for (int r = 0; r < 4; r++) {
                const int m = m0 + wm + i*16 + quad*4 + r;
                const int n = n0 + wn + j*16 + ln;     // 0..3071
                const int b_ = m >> 11;
                const int s  = m & 2047;
                const int which = n >> 10;             // 0=Q 1=K 2=V
                const int nn = n & 1023;
                const int h  = nn >> 6;
                const int d  = nn & 63;
                const __hip_bfloat16 v = __float2bfloat16(acc[i][j][r]);
                if (which == 0)
                    q_out[((size_t)((b_*NH + h)*SL + s))*DK + d] = v;
                else if (which == 1)
                    k_out[((size_t)((b_*NH + h)*SL + s))*DK + d] = v;
                else
                    v_out[((size_t)((b_*NH + h)*DK + d))*SL + s] = v;
            }
        }
    }
}

// ---------------------------------------------------------------------------
// Pure-bf16 GEMM (final projection), same BK=64 + swizzle structure.
// ---------------------------------------------------------------------------
__global__ __launch_bounds__(256)
void gemm_wo(const __hip_bfloat16* __restrict__ A,
             const __hip_bfloat16* __restrict__ W,
             float* __restrict__ outp)
{
    __shared__ __hip_bfloat16 As[128 * 64];
    __shared__ __hip_bfloat16 Bs[128 * 64];
    const int tid  = threadIdx.x;
    const int m0   = blockIdx.x * 128;
    const int n0   = blockIdx.y * 128;
    const int w    = tid >> 6;
    const int lane = tid & 63;
    const int quad = lane >> 4;
    const int ln   = lane & 15;
    const int wm   = (w & 1) * 64;
    const int wn   = (w >> 1) * 64;
    const int srow = lane >> 3;
    const int sch  = ((lane & 7) ^ srow) * 8;

    f32x4 acc[4][4] = {};

    for (int k0 = 0; k0 < DM; k0 += 64) {
        #pragma unroll
        for (int j = 0; j < 4; j++) {
            const int rbase = w * 32 + j * 8;
            async_copy16(A + (size_t)(m0 + rbase + srow) * DM + k0 + sch,
                         &As[rbase * 64]);
            async_copy16(W + (size_t)(n0 + rbase + srow) * DM + k0 + sch,
                         &Bs[rbase * 64]);
        }
        __syncthreads();

        #pragma unroll
        for (int ks = 0; ks < 2; ks++) {
            short8 a[4], b[4];
            #pragma unroll
            for (int i = 0; i < 4; i++)
                a[i] = *reinterpret_cast<const short8*>(
                    &As[(wm + i*16 + ln) * 64 + (((ks*4 + quad) ^ (ln & 7)) * 8)]);
            #pragma unroll
            for (int j = 0; j < 4; j++)
                b[j] = *reinterpret_cast<const short8*>(
                    &Bs[(wn + j*16 + ln) * 64 + (((ks*4 + quad) ^ (ln & 7)) * 8)]);
            #pragma unroll
            for (int i = 0; i < 4; i++)
                #pragma unroll
                for (int j = 0; j < 4; j++)
                    acc[i][j] = __builtin_amdgcn_mfma_f32_16x16x32_bf16(a[i], b[j], acc[i][j], 0, 0, 0);
        }
        __syncthreads();
    }

    #pragma unroll
    for (int i = 0; i < 4; i++)
        #pragma unroll
        for (int j = 0; j < 4; j++)
            #pragma unroll
            for (int r = 0; r < 4; r++) {
                const int m = m0 + wm + i*16 + quad*4 + r;
                const int n = n0 + wn + j*16 + ln;
                outp[(size_t)m * DM + n] = acc[i][j][r];
            }
}

// ---------------------------------------------------------------------------
// Fallback GEMM (round-7 proven): fp32 inputs, convert during staging.
// ---------------------------------------------------------------------------
template<bool A_BF16, int MODE>
__global__ __launch_bounds__(256)
void gemm_bt(const void* __restrict__ Ap,
             const float* __restrict__ W,
             void* __restrict__ outp)
{
    __shared__ __hip_bfloat16 As[128][40];
    __shared__ __hip_bfloat16 Bs[128][40];
    const int tid  = threadIdx.x;
    const int m0   = blockIdx.x * 128;
    const int n0   = blockIdx.y * 128;
    const int w    = tid >> 6;
    const int lane = tid & 63;
    const int quad = lane >> 4;
    const int ln   = lane & 15;
    const int wm   = (w & 1) * 64;
    const int wn   = (w >> 1) * 64;
    const int lr   = tid >> 1;
    const int lc   = (tid & 1) * 16;

    f32x4 acc[4][4] = {};

    for (int k0 = 0; k0 < DM; k0 += 32) {
        if (A_BF16) {
            const uint4* ap = reinterpret_cast<const uint4*>(
                (const __hip_bfloat16*)Ap + (size_t)(m0 + lr) * DM + k0 + lc);
            uint4 a0 = ap[0], a1 = ap[1];
            *reinterpret_cast<uint4*>(&As[lr][lc])     = a0;
            *reinterpret_cast<uint4*>(&As[lr][lc + 8]) = a1;
        } else {
            const float4* ap = reinterpret_cast<const float4*>(
                (const float*)Ap + (size_t)(m0 + lr) * DM + k0 + lc);
            float4 f0 = ap[0], f1 = ap[1], f2 = ap[2], f3 = ap[3];
            PackB p0, p1;
            p0.h[0] = __float2bfloat16(f0.x); p0.h[1] = __float2bfloat16(f0.y);
            p0.h[2] = __float2bfloat16(f0.z); p0.h[3] = __float2bfloat16(f0.w);
            p0.h[4] = __float2bfloat16(f1.x); p0.h[5] = __float2bfloat16(f1.y);
            p0.h[6] = __float2bfloat16(f1.z); p0.h[7] = __float2bfloat16(f1.w);
            p1.h[0] = __float2bfloat16(f2.x); p1.h[1] = __float2bfloat16(f2.y);
            p1.h[2] = __float2bfloat16(f2.z); p1.h[3] = __float2bfloat16(f2.w);
            p1.h[4] = __float2bfloat16(f3.x); p1.h[5] = __float2bfloat16(f3.y);
            p1.h[6] = __float2bfloat16(f3.z); p1.h[7] = __float2bfloat16(f3.w);
            *reinterpret_cast<uint4*>(&As[lr][lc])     = p0.u;
            *reinterpret_cast<uint4*>(&As[lr][lc + 8]) = p1.u;
        }
        {
            const float4* wp = reinterpret_cast<const float4*>(
                W + (size_t)(n0 + lr) * DM + k0 + lc);
            float4 f0 = wp[0], f1 = wp[1], f2 = wp[2], f3 = wp[3];
            PackB p0, p1;
            p0.h[0] = __float2bfloat16(f0.x); p0.h[1] = __float2bfloat16(f0.y);
            p0.h[2] = __float2bfloat16(f0.z); p0.h[3] = __float2bfloat16(f0.w);
            p0.h[4] = __float2bfloat16(f1.x); p0.h[5] = __float2bfloat16(f1.y);
            p0.h[6] = __float2bfloat16(f1.z); p0.h[7] = __float2bfloat16(f1.w);
            p1.h[0] = __float2bfloat16(f2.x); p1.h[1] = __float2bfloat16(f2.y);
            p1.h[2] = __float2bfloat16(f2.z); p1.h[3] = __float2bfloat16(f2.w);
            p1.h[4] = __float2bfloat16(f3.x); p1.h[5] = __float2bfloat16(f3.y);
            p1.h[6] = __float2bfloat16(f3.z); p1.h[7] = __float2bfloat16(f3.w);
            *reinterpret_cast<uint4*>(&Bs[lr][lc])     = p0.u;
            *reinterpret_cast<uint4*>(&Bs[lr][lc + 8]) = p1.u;
        }
        __syncthreads();

        short8 a[4], b[4];
        #pragma unroll
        for (int i = 0; i < 4; i++)
            a[i] = *reinterpret_cast<const short8*>(&As[wm + i*16 + ln][quad*8]);
        #pragma unroll
        for (int j = 0; j < 4; j++)
            b[j] = *reinterpret_cast<const short8*>(&Bs[wn + j*16 + ln][quad*8]);
        #pragma unroll
        for (int i = 0; i < 4; i++)
            #pragma unroll
            for (int j = 0; j < 4; j++)
                acc[i][j] = __builtin_amdgcn_mfma_f32_16x16x32_bf16(a[i], b[j], acc[i][j], 0, 0, 0);
        __syncthreads();
    }

    #pragma unroll
    for (int i = 0; i < 4; i++) {
        #pragma unroll
        for (int j = 0; j < 4; j++) {
            #pragma unroll
            for (int r = 0; r < 4; r++) {
                const int m = m0 + wm + i*16 + quad*4 + r;
                const int n = n0 + wn + j*16 + ln;
                const float v = acc[i][j][r];
                if (MODE == 2) {
                    ((float*)outp)[(size_t)m * DM + n] = v;
                } else {
                    const int b_ = m >> 11;
                    const int s  = m & 2047;
                    const int h  = n >> 6;
                    const int d  = n & 63;
                    size_t idx;
                    if (MODE == 0) idx = ((size_t)((b_*NH + h)*SL + s))*DK + d;
                    else           idx = ((size_t)((b_*NH + h)*DK + d))*SL + s;
                    ((__hip_bfloat16*)outp)[idx] = __float2bfloat16(v);
                }
            }
        }
    }
}

// ---------------------------------------------------------------------------
// Causal flash attention, LDS-staged K/V tiles.
// T14 async-stage split: loads for tile t+1 are ISSUED before compute of
// tile t; their vmcnt drain happens at the ds_write after the next barrier,
// so HBM latency hides under QK+softmax+PV.  T5: setprio(1) around MFMA
// clusters (attn is the structure where it pays, m191).
// ---------------------------------------------------------------------------
__global__ __launch_bounds__(256)
void attn_causal(const __hip_bfloat16* __restrict__ Q,
                 const __hip_bfloat16* __restrict__ K,
                 const __hip_bfloat16* __restrict__ Vt,
                 __hip_bfloat16* __restrict__ O)
{
    __shared__ __hip_bfloat16 Ks[64][72];
    __shared__ __hip_bfloat16 Vs[64][72];
    __shared__ __hip_bfloat16 p_lds[4][16][72];

    const int tid  = threadIdx.x;
    const int w    = tid >> 6;
    const int lane = tid & 63;
    const int quad = lane >> 4;
    const int ln   = lane & 15;
    const int bh   = blockIdx.y;
    const int b_   = bh >> 4;
    const int h    = bh & 15;

    const int srow   = tid >> 3;
    const int schunk = (tid & 7) * 8;

    const __hip_bfloat16* Qb = Q  + (size_t)bh * SL * DK;
    const __hip_bfloat16* Kb = K  + (size_t)bh * SL * DK;
    const __hip_bfloat16* Vb = Vt + (size_t)bh * DK * SL;

    for (int pass = 0; pass < 2; ++pass) {
        const int qt    = (pass == 0) ? (int)blockIdx.x : 31 - (int)blockIdx.x;
        const int q0    = qt * 64;
        const int qbase = q0 + w * 16;

        short8 aq0 = *reinterpret_cast<const short8*>(Qb + (size_t)(qbase + ln) * DK + quad*8);
        short8 aq1 = *reinterpret_cast<const short8*>(Qb + (size_t)(qbase + ln) * DK + 32 + quad*8);

        f32x4 acc[4] = {};
        float lsum[4] = {0.f, 0.f, 0.f, 0.f};

        // prologue: prefetch tile 0 into registers
        const __hip_bfloat16* Kg = Kb + (size_t)srow * DK + schunk;
        const __hip_bfloat16* Vg = Vb + (size_t)srow * SL + schunk;
        uint4 kv0 = *reinterpret_cast<const uint4*>(Kg);
        uint4 kv1 = *reinterpret_cast<const uint4*>(Kg + 32 * DK);
        uint4 vv0 = *reinterpret_cast<const uint4*>(Vg);
        uint4 vv1 = *reinterpret_cast<const uint4*>(Vg + 32 * SL);

        for (int k0 = 0; k0 <= q0; k0 += 64) {
            __syncthreads();       // prior tile's LDS reads complete
            *reinterpret_cast<uint4*>(&Ks[srow     ][schunk]) = kv0;
            *reinterpret_cast<uint4*>(&Ks[srow + 32][schunk]) = kv1;
            *reinterpret_cast<uint4*>(&Vs[srow     ][schunk]) = vv0;
            *reinterpret_cast<uint4*>(&Vs[srow + 32][schunk]) = vv1;
            __syncthreads();

            // issue next tile's loads now; they drain at next iter's ds_write
            if (k0 + 64 <= q0) {
                const __hip_bfloat16* Kg2 = Kb + (size_t)(k0 + 64 + srow) * DK + schunk;
                const __hip_bfloat16* Vg2 = Vb + (size_t)srow * SL + (k0 + 64) + schunk;
                kv0 = *reinterpret_cast<const uint4*>(Kg2);
                kv1 = *reinterpret_cast<const uint4*>(Kg2 + 32 * DK);
                vv0 = *reinterpret_cast<const uint4*>(Vg2);
                vv1 = *reinterpret_cast<const uint4*>(Vg2 + 32 * SL);
            }

            f32x4 s[4];
            __builtin_amdgcn_s_setprio(1);
            #pragma unroll
            for (int kc = 0; kc < 4; kc++) {
                short8 bk0 = *reinterpret_cast<const short8*>(&Ks[kc*16 + ln][quad*8]);
                short8 bk1 = *reinterpret_cast<const short8*>(&Ks[kc*16 + ln][32 + quad*8]);
                f32x4 z = {};
                z = __builtin_amdgcn_mfma_f32_16x16x32_bf16(aq0, bk0, z, 0, 0, 0);
                z = __builtin_amdgcn_mfma_f32_16x16x32_bf16(aq1, bk1, z, 0, 0, 0);
                s[kc] = z;
            }
            __builtin_amdgcn_s_setprio(0);
            const bool diag = (k0 == q0);
            #pragma unroll
            for (int kc = 0; kc < 4; kc++) {
                #pragma unroll
                for (int r = 0; r < 4; r++) {
                    float v = s[kc][r] * SC_LOG2E;
                    if (diag) {
                        const int kg = k0 + kc*16 + ln;
                        const int qg = qbase + quad*4 + r;
                        if (kg > qg) v = NEG_BIG;
                    }
                    const float p = __builtin_amdgcn_exp2f(v);
                    lsum[r] += p;
                    p_lds[w][quad*4 + r][kc*16 + ln] = __float2bfloat16(p);
                }
            }
            short8 ap0 = *reinterpret_cast<const short8*>(&p_lds[w][ln][quad*8]);
            short8 ap1 = *reinterpret_cast<const short8*>(&p_lds[w][ln][32 + quad*8]);
            __builtin_amdgcn_s_setprio(1);
            #pragma unroll
            for (int nt = 0; nt < 4; nt++) {
                short8 bv0 = *reinterpret_cast<const short8*>(&Vs[nt*16 + ln][quad*8]);
                short8 bv1 = *reinterpret_cast<const short8*>(&Vs[nt*16 + ln][32 + quad*8]);
                acc[nt] = __builtin_amdgcn_mfma_f32_16x16x32_bf16(ap0, bv0, acc[nt], 0, 0, 0);
                acc[nt] = __builtin_amdgcn_mfma_f32_16x16x32_bf16(ap1, bv1, acc[nt], 0, 0, 0);
            }
            __builtin_amdgcn_s_setprio(0);
        }

        #pragma unroll
        for (int r = 0; r < 4; r++) {
            float v = lsum[r];
            v += __shfl_xor(v, 1, 64);
            v += __shfl_xor(v, 2, 64);
            v += __shfl_xor(v, 4, 64);
            v += __shfl_xor(v, 8, 64);
            lsum[r] = v;
        }

        #pragma unroll
        for (int nt = 0; nt < 4; nt++) {
            #pragma unroll
            for (int r = 0; r < 4; r++) {
                const int sI = qbase + quad*4 + r;
                const int d  = nt*16 + ln;
                const float v = acc[nt][r] / lsum[r];
                O[(((size_t)b_ * SL + sI) * NH + h) * DK + d] = __float2bfloat16(v);
            }
        }
    }
}

// ---------------------------------------------------------------------------
// ws layout (fast path, 72 MiB): [q 16M][k 16M][v 16M][xb 16M][wq 2M][wk 2M]
// [wv 2M][wo 2M]. Attention O reuses xb (dead after projections); Wo GEMM
// writes fp32 directly to d_out (no copy).
// ---------------------------------------------------------------------------
extern "C" void kernel_launch(void* const* d_in, const int* in_sizes, int n_in,
                              void* d_out, int out_size, void* d_ws, size_t ws_size,
                              hipStream_t stream)
{
    const float* x  = (const float*)d_in[0];
    const float* Wq = (const float*)d_in[1];
    const float* Wk = (const float*)d_in[2];
    const float* Wv = (const float*)d_in[3];
    const float* Wo = (const float*)d_in[4];

    __hip_bfloat16* q_ws = (__hip_bfloat16*)d_ws;
    __hip_bfloat16* k_ws = q_ws + QKV_ELEMS;
    __hip_bfloat16* v_ws = k_ws + QKV_ELEMS;

    const dim3 gb(256);
    const size_t FAST_WS = (3 * QKV_ELEMS + QKV_ELEMS + 4 * (size_t)DM * DM)
                           * sizeof(__hip_bfloat16);   // 72 MiB

    if (ws_size >= FAST_WS) {
        __hip_bfloat16* xb  = v_ws + QKV_ELEMS;
        __hip_bfloat16* wqb = xb  + QKV_ELEMS;        // [Wq;Wk;Wv] contiguous
        __hip_bfloat16* wob = wqb + 3 * (size_t)DM * DM;

        cvt_all<<<12288, 256, 0, stream>>>(x, Wq, Wk, Wv, Wo, xb);

        gemm_qkv<<<dim3(64, 24), gb, 0, stream>>>(xb, wqb, q_ws, k_ws, v_ws);

        attn_causal<<<dim3(16, BB*NH), 256, 0, stream>>>(q_ws, k_ws, v_ws, xb);

        gemm_wo<<<dim3(64, 8), gb, 0, stream>>>(xb, wob, (float*)d_out);
    } else {
        __hip_bfloat16* obuf = (__hip_bfloat16*)d_out;
        float*          fbuf = (float*)d_ws;
        const dim3 gg(64, 8);
        gemm_bt<false, 0><<<gg, gb, 0, stream>>>(x, Wq, q_ws);
        gemm_bt<false, 0><<<gg, gb, 0, stream>>>(x, Wk, k_ws);
        gemm_bt<false, 1><<<gg, gb, 0, stream>>>(x, Wv, v_ws);
        attn_causal<<<dim3(16, BB*NH), 256, 0, stream>>>(q_ws, k_ws, v_ws, obuf);
        gemm_bt<true, 2><<<gg, gb, 0, stream>>>(obuf, Wo, fbuf);
        (void)hipMemcpyAsync(d_out, fbuf, QKV_ELEMS * sizeof(float),
                             hipMemcpyDeviceToDevice, stream);
    }
}

// Round 2
// 256.280 us; speedup vs baseline: 1.1555x; 1.1555x over previous
//
#include <hip/hip_runtime.h>
#include <hip/hip_bf16.h>

typedef __attribute__((ext_vector_type(8))) short short8;
typedef __attribute__((ext_vector_type(4))) float f32x4;
typedef __attribute__((ext_vector_type(16))) float f32x16;

static constexpr int DM = 1024;   // d_model
static constexpr int NH = 16;     // heads
static constexpr int DK = 64;     // head dim
static constexpr int SL = 2048;   // seq len
static constexpr int BB = 4;      // batch
static constexpr size_t QKV_ELEMS = (size_t)BB * NH * SL * DK;  // 8388608
static constexpr float NEG_BIG = -30000.0f;          // exp2 -> 0
static constexpr float SC_LOG2E = 0.125f * 1.44269504088896340736f; // /sqrt(64)*log2(e)

union PackB { __hip_bfloat16 h[8]; uint4 u; };
union Pack4 { __hip_bfloat16 h[4]; uint2 u; };

// async global->LDS, 16 B per lane (dest = wave-uniform base + lane*16)
typedef __attribute__((address_space(1))) unsigned int gu32;
typedef __attribute__((address_space(3))) unsigned int lu32;
__device__ __forceinline__ void async_copy16(const void* g, void* l) {
    __builtin_amdgcn_global_load_lds((gu32*)g, (lu32*)l, 16, 0, 0);
}

// pack two f32 -> two bf16 in one u32 (low = first arg)
__device__ __forceinline__ unsigned cvt_pk_bf16(float lo, float hi) {
    unsigned r;
    asm("v_cvt_pk_bf16_f32 %0, %1, %2" : "=v"(r) : "v"(lo), "v"(hi));
    return r;
}
// swap: a.hi <-> b.lo  (new_a[l>=32]=b[l-32], new_b[l<32]=a[l+32])
__device__ __forceinline__ void pl32_swap(unsigned &a, unsigned &b) {
    asm("v_permlane32_swap_b32 %0, %1" : "+v"(a), "+v"(b));
}

// ---------------------------------------------------------------------------
// Bulk fp32 -> bf16 convert: x (8M elems) then Wq,Wk,Wv,Wo (1M each) into one
// contiguous bf16 region. One float4 per thread.
// ---------------------------------------------------------------------------
__global__ __launch_bounds__(256)
void cvt_all(const float* __restrict__ x,
             const float* __restrict__ wq, const float* __restrict__ wk,
             const float* __restrict__ wv, const float* __restrict__ wo,
             __hip_bfloat16* __restrict__ dst)
{
    const size_t i = (size_t)blockIdx.x * 256 + threadIdx.x;  // float4 index
    const float* src; size_t local;
    if (i < 2097152) { src = x; local = i; }
    else {
        const size_t j = i - 2097152;
        const int r = (int)(j >> 18);           // 262144 float4 per W
        local = j & 262143;
        src = (r == 0) ? wq : (r == 1) ? wk : (r == 2) ? wv : wo;
    }
    float4 f = reinterpret_cast<const float4*>(src)[local];
    Pack4 p;
    p.h[0] = __float2bfloat16(f.x); p.h[1] = __float2bfloat16(f.y);
    p.h[2] = __float2bfloat16(f.z); p.h[3] = __float2bfloat16(f.w);
    reinterpret_cast<uint2*>(dst)[i] = p.u;
}

// ---------------------------------------------------------------------------
// Fused QKV projection, BK=64 single-buffered (round-1, kept).
// ---------------------------------------------------------------------------
__global__ __launch_bounds__(256)
void gemm_qkv(const __hip_bfloat16* __restrict__ A,
              const __hip_bfloat16* __restrict__ W,
              __hip_bfloat16* __restrict__ q_out,
              __hip_bfloat16* __restrict__ k_out,
              __hip_bfloat16* __restrict__ v_out)
{
    __shared__ __hip_bfloat16 As[128 * 64];   // contiguous: global_load_lds order
    __shared__ __hip_bfloat16 Bs[128 * 64];
    const int tid  = threadIdx.x;
    const int m0   = blockIdx.x * 128;
    const int n0   = blockIdx.y * 128;
    const int w    = tid >> 6;
    const int lane = tid & 63;
    const int quad = lane >> 4;
    const int ln   = lane & 15;
    const int wm   = (w & 1) * 64;
    const int wn   = (w >> 1) * 64;
    const int srow = lane >> 3;                    // 0..7
    const int sch  = ((lane & 7) ^ srow) * 8;      // swizzled source chunk

    f32x4 acc[4][4] = {};

    for (int k0 = 0; k0 < DM; k0 += 64) {
        #pragma unroll
        for (int j = 0; j < 4; j++) {
            const int rbase = w * 32 + j * 8;      // multiple of 8: stripe-aligned
            async_copy16(A + (size_t)(m0 + rbase + srow) * DM + k0 + sch,
                         &As[rbase * 64]);
            async_copy16(W + (size_t)(n0 + rbase + srow) * DM + k0 + sch,
                         &Bs[rbase * 64]);
        }
        __syncthreads();

        #pragma unroll
        for (int ks = 0; ks < 2; ks++) {
            short8 a[4], b[4];
            #pragma unroll
            for (int i = 0; i < 4; i++)
                a[i] = *reinterpret_cast<const short8*>(
                    &As[(wm + i*16 + ln) * 64 + (((ks*4 + quad) ^ (ln & 7)) * 8)]);
            #pragma unroll
            for (int j = 0; j < 4; j++)
                b[j] = *reinterpret_cast<const short8*>(
                    &Bs[(wn + j*16 + ln) * 64 + (((ks*4 + quad) ^ (ln & 7)) * 8)]);
            #pragma unroll
            for (int i = 0; i < 4; i++)
                #pragma unroll
                for (int j = 0; j < 4; j++)
                    acc[i][j] = __builtin_amdgcn_mfma_f32_16x16x32_bf16(a[i], b[j], acc[i][j], 0, 0, 0);
        }
        __syncthreads();
    }

    // Epilogue: C/D layout col=lane&15, row=quad*4+reg  [m89/m91]
    #pragma unroll
    for (int i = 0; i < 4; i++) {
        #pragma unroll
        for (int j = 0; j < 4; j++) {
            #pragma unroll
            for (int r = 0; r < 4; r++) {
                const int m = m0 + wm + i*16 + quad*4 + r;
                const int n = n0 + wn + j*16 + ln;     // 0..3071
                const int b_ = m >> 11;
                const int s  = m & 2047;
                const int which = n >> 10;             // 0=Q 1=K 2=V
                const int nn = n & 1023;
                const int h  = nn >> 6;
                const int d  = nn & 63;
                const __hip_bfloat16 v = __float2bfloat16(acc[i][j][r]);
                if (which == 0)
                    q_out[((size_t)((b_*NH + h)*SL + s))*DK + d] = v;
                else if (which == 1)
                    k_out[((size_t)((b_*NH + h)*SL + s))*DK + d] = v;
                else
                    v_out[((size_t)((b_*NH + h)*DK + d))*SL + s] = v;
            }
        }
    }
}

// ---------------------------------------------------------------------------
// Pure-bf16 GEMM (final projection), BK=64 + swizzle (round-1, kept).
// ---------------------------------------------------------------------------
__global__ __launch_bounds__(256)
void gemm_wo(const __hip_bfloat16* __restrict__ A,
             const __hip_bfloat16* __restrict__ W,
             float* __restrict__ outp)
{
    __shared__ __hip_bfloat16 As[128 * 64];
    __shared__ __hip_bfloat16 Bs[128 * 64];
    const int tid  = threadIdx.x;
    const int m0   = blockIdx.x * 128;
    const int n0   = blockIdx.y * 128;
    const int w    = tid >> 6;
    const int lane = tid & 63;
    const int quad = lane >> 4;
    const int ln   = lane & 15;
    const int wm   = (w & 1) * 64;
    const int wn   = (w >> 1) * 64;
    const int srow = lane >> 3;
    const int sch  = ((lane & 7) ^ srow) * 8;

    f32x4 acc[4][4] = {};

    for (int k0 = 0; k0 < DM; k0 += 64) {
        #pragma unroll
        for (int j = 0; j < 4; j++) {
            const int rbase = w * 32 + j * 8;
            async_copy16(A + (size_t)(m0 + rbase + srow) * DM + k0 + sch,
                         &As[rbase * 64]);
            async_copy16(W + (size_t)(n0 + rbase + srow) * DM + k0 + sch,
                         &Bs[rbase * 64]);
        }
        __syncthreads();

        #pragma unroll
        for (int ks = 0; ks < 2; ks++) {
            short8 a[4], b[4];
            #pragma unroll
            for (int i = 0; i < 4; i++)
                a[i] = *reinterpret_cast<const short8*>(
                    &As[(wm + i*16 + ln) * 64 + (((ks*4 + quad) ^ (ln & 7)) * 8)]);
            #pragma unroll
            for (int j = 0; j < 4; j++)
                b[j] = *reinterpret_cast<const short8*>(
                    &Bs[(wn + j*16 + ln) * 64 + (((ks*4 + quad) ^ (ln & 7)) * 8)]);
            #pragma unroll
            for (int i = 0; i < 4; i++)
                #pragma unroll
                for (int j = 0; j < 4; j++)
                    acc[i][j] = __builtin_amdgcn_mfma_f32_16x16x32_bf16(a[i], b[j], acc[i][j], 0, 0, 0);
        }
        __syncthreads();
    }

    #pragma unroll
    for (int i = 0; i < 4; i++)
        #pragma unroll
        for (int j = 0; j < 4; j++)
            #pragma unroll
            for (int r = 0; r < 4; r++) {
                const int m = m0 + wm + i*16 + quad*4 + r;
                const int n = n0 + wn + j*16 + ln;
                outp[(size_t)m * DM + n] = acc[i][j][r];
            }
}

// ---------------------------------------------------------------------------
// Fallback GEMM (round-7 proven): fp32 inputs, convert during staging.
// ---------------------------------------------------------------------------
template<bool A_BF16, int MODE>
__global__ __launch_bounds__(256)
void gemm_bt(const void* __restrict__ Ap,
             const float* __restrict__ W,
             void* __restrict__ outp)
{
    __shared__ __hip_bfloat16 As[128][40];
    __shared__ __hip_bfloat16 Bs[128][40];
    const int tid  = threadIdx.x;
    const int m0   = blockIdx.x * 128;
    const int n0   = blockIdx.y * 128;
    const int w    = tid >> 6;
    const int lane = tid & 63;
    const int quad = lane >> 4;
    const int ln   = lane & 15;
    const int wm   = (w & 1) * 64;
    const int wn   = (w >> 1) * 64;
    const int lr   = tid >> 1;
    const int lc   = (tid & 1) * 16;

    f32x4 acc[4][4] = {};

    for (int k0 = 0; k0 < DM; k0 += 32) {
        if (A_BF16) {
            const uint4* ap = reinterpret_cast<const uint4*>(
                (const __hip_bfloat16*)Ap + (size_t)(m0 + lr) * DM + k0 + lc);
            uint4 a0 = ap[0], a1 = ap[1];
            *reinterpret_cast<uint4*>(&As[lr][lc])     = a0;
            *reinterpret_cast<uint4*>(&As[lr][lc + 8]) = a1;
        } else {
            const float4* ap = reinterpret_cast<const float4*>(
                (const float*)Ap + (size_t)(m0 + lr) * DM + k0 + lc);
            float4 f0 = ap[0], f1 = ap[1], f2 = ap[2], f3 = ap[3];
            PackB p0, p1;
            p0.h[0] = __float2bfloat16(f0.x); p0.h[1] = __float2bfloat16(f0.y);
            p0.h[2] = __float2bfloat16(f0.z); p0.h[3] = __float2bfloat16(f0.w);
            p0.h[4] = __float2bfloat16(f1.x); p0.h[5] = __float2bfloat16(f1.y);
            p0.h[6] = __float2bfloat16(f1.z); p0.h[7] = __float2bfloat16(f1.w);
            p1.h[0] = __float2bfloat16(f2.x); p1.h[1] = __float2bfloat16(f2.y);
            p1.h[2] = __float2bfloat16(f2.z); p1.h[3] = __float2bfloat16(f2.w);
            p1.h[4] = __float2bfloat16(f3.x); p1.h[5] = __float2bfloat16(f3.y);
            p1.h[6] = __float2bfloat16(f3.z); p1.h[7] = __float2bfloat16(f3.w);
            *reinterpret_cast<uint4*>(&As[lr][lc])     = p0.u;
            *reinterpret_cast<uint4*>(&As[lr][lc + 8]) = p1.u;
        }
        {
            const float4* wp = reinterpret_cast<const float4*>(
                W + (size_t)(n0 + lr) * DM + k0 + lc);
            float4 f0 = wp[0], f1 = wp[1], f2 = wp[2], f3 = wp[3];
            PackB p0, p1;
            p0.h[0] = __float2bfloat16(f0.x); p0.h[1] = __float2bfloat16(f0.y);
            p0.h[2] = __float2bfloat16(f0.z); p0.h[3] = __float2bfloat16(f0.w);
            p0.h[4] = __float2bfloat16(f1.x); p0.h[5] = __float2bfloat16(f1.y);
            p0.h[6] = __float2bfloat16(f1.z); p0.h[7] = __float2bfloat16(f1.w);
            p1.h[0] = __float2bfloat16(f2.x); p1.h[1] = __float2bfloat16(f2.y);
            p1.h[2] = __float2bfloat16(f2.z); p1.h[3] = __float2bfloat16(f2.w);
            p1.h[4] = __float2bfloat16(f3.x); p1.h[5] = __float2bfloat16(f3.y);
            p1.h[6] = __float2bfloat16(f3.z); p1.h[7] = __float2bfloat16(f3.w);
            *reinterpret_cast<uint4*>(&Bs[lr][lc])     = p0.u;
            *reinterpret_cast<uint4*>(&Bs[lr][lc + 8]) = p1.u;
        }
        __syncthreads();

        short8 a[4], b[4];
        #pragma unroll
        for (int i = 0; i < 4; i++)
            a[i] = *reinterpret_cast<const short8*>(&As[wm + i*16 + ln][quad*8]);
        #pragma unroll
        for (int j = 0; j < 4; j++)
            b[j] = *reinterpret_cast<const short8*>(&Bs[wn + j*16 + ln][quad*8]);
        #pragma unroll
        for (int i = 0; i < 4; i++)
            #pragma unroll
            for (int j = 0; j < 4; j++)
                acc[i][j] = __builtin_amdgcn_mfma_f32_16x16x32_bf16(a[i], b[j], acc[i][j], 0, 0, 0);
        __syncthreads();
    }

    #pragma unroll
    for (int i = 0; i < 4; i++) {
        #pragma unroll
        for (int j = 0; j < 4; j++) {
            #pragma unroll
            for (int r = 0; r < 4; r++) {
                const int m = m0 + wm + i*16 + quad*4 + r;
                const int n = n0 + wn + j*16 + ln;
                const float v = acc[i][j][r];
                if (MODE == 2) {
                    ((float*)outp)[(size_t)m * DM + n] = v;
                } else {
                    const int b_ = m >> 11;
                    const int s  = m & 2047;
                    const int h  = n >> 6;
                    const int d  = n & 63;
                    size_t idx;
                    if (MODE == 0) idx = ((size_t)((b_*NH + h)*SL + s))*DK + d;
                    else           idx = ((size_t)((b_*NH + h)*DK + d))*SL + s;
                    ((__hip_bfloat16*)outp)[idx] = __float2bfloat16(v);
                }
            }
        }
    }
}

// ---------------------------------------------------------------------------
// Causal flash attention, 32x32 swapped-operand form (guide §B / T12).
// - QBLK=128 (wave owns 32 q-rows), KVBLK=64, grid (8, B*H), 2-pass balance.
// - QK: mfma(K, Q): A=K from LDS, B=Q in regs; D col = q (lane&31),
//   row(reg) = k = (r&3)+8*(r>>2)+4*(lane>>5)   [m74/m101]
// - P stays in registers: per 16-k chunk c, regs 8(c&1)..+3 (X) and +4..+7 (Y)
//   are cvt_pk'd to bf16 and permlane32_swap'd to assemble the PV B-fragment
//   (no p_lds round-trip at all).
// - PV: mfma(V^T, P): A=V^T rows d from LDS; out O^T[d][q] accumulates in regs.
// - lsum: per-lane partial + one shfl_xor(32); direct b64 epilogue stores.
// ---------------------------------------------------------------------------
__global__ __launch_bounds__(256)
void attn_causal(const __hip_bfloat16* __restrict__ Q,
                 const __hip_bfloat16* __restrict__ K,
                 const __hip_bfloat16* __restrict__ Vt,
                 __hip_bfloat16* __restrict__ O)
{
    __shared__ __hip_bfloat16 Ks[64][72];   // [k][d], +8 pad: bank-uniform
    __shared__ __hip_bfloat16 Vs[64][72];   // [d][k]

    const int tid  = threadIdx.x;
    const int w    = tid >> 6;
    const int lane = tid & 63;
    const int ln32 = lane & 31;
    const int hi   = lane >> 5;
    const int bh   = blockIdx.y;
    const int b_   = bh >> 4;
    const int h    = bh & 15;

    const int sr = tid >> 3;         // staging row 0..31
    const int sc = (tid & 7) * 8;    // staging chunk (elements)

    const __hip_bfloat16* Qb = Q  + (size_t)bh * SL * DK;
    const __hip_bfloat16* Kb = K  + (size_t)bh * SL * DK;
    const __hip_bfloat16* Vb = Vt + (size_t)bh * DK * SL;

    for (int pass = 0; pass < 2; ++pass) {
        const int qt    = (pass == 0) ? (int)blockIdx.x : 15 - (int)blockIdx.x;
        const int q0    = qt * 128;
        const int qbase = q0 + w * 32;
        const int qg    = qbase + ln32;       // this lane's q row

        short8 qf[4];
        #pragma unroll
        for (int dt = 0; dt < 4; dt++)
            qf[dt] = *reinterpret_cast<const short8*>(
                Qb + (size_t)qg * DK + dt*16 + hi*8);

        f32x16 o0 = {}, o1 = {};
        float lsum = 0.f;

        const int nkt = 2*qt + 2;

        // prefetch tile 0 into registers (T14)
        uint4 kr0 = *reinterpret_cast<const uint4*>(Kb + (size_t)sr * DK + sc);
        uint4 kr1 = *reinterpret_cast<const uint4*>(Kb + (size_t)(32 + sr) * DK + sc);
        uint4 vr0 = *reinterpret_cast<const uint4*>(Vb + (size_t)sr * SL + sc);
        uint4 vr1 = *reinterpret_cast<const uint4*>(Vb + (size_t)(32 + sr) * SL + sc);

        for (int it = 0; it < nkt; ++it) {
            const int k0 = it * 64;
            __syncthreads();                 // prior tile's LDS reads done
            *reinterpret_cast<uint4*>(&Ks[sr     ][sc]) = kr0;
            *reinterpret_cast<uint4*>(&Ks[sr + 32][sc]) = kr1;
            *reinterpret_cast<uint4*>(&Vs[sr     ][sc]) = vr0;
            *reinterpret_cast<uint4*>(&Vs[sr + 32][sc]) = vr1;
            __syncthreads();
            if (it + 1 < nkt) {              // issue next tile's loads now
                const int kn = k0 + 64;
                kr0 = *reinterpret_cast<const uint4*>(Kb + (size_t)(kn + sr) * DK + sc);
                kr1 = *reinterpret_cast<const uint4*>(Kb + (size_t)(kn + 32 + sr) * DK + sc);
                vr0 = *reinterpret_cast<const uint4*>(Vb + (size_t)sr * SL + kn + sc);
                vr1 = *reinterpret_cast<const uint4*>(Vb + (size_t)(32 + sr) * SL + kn + sc);
            }
            if (k0 > qbase + 31) continue;   // wave-uniform: fully masked tile

            // ---- QK^T (swapped): S[k][q] ----
            f32x16 s0 = {}, s1 = {};
            __builtin_amdgcn_s_setprio(1);
            #pragma unroll
            for (int dt = 0; dt < 4; dt++) {
                short8 kf0 = *reinterpret_cast<const short8*>(&Ks[ln32     ][dt*16 + hi*8]);
                short8 kf1 = *reinterpret_cast<const short8*>(&Ks[32 + ln32][dt*16 + hi*8]);
                s0 = __builtin_amdgcn_mfma_f32_32x32x16_bf16(kf0, qf[dt], s0, 0, 0, 0);
                s1 = __builtin_amdgcn_mfma_f32_32x32x16_bf16(kf1, qf[dt], s1, 0, 0, 0);
            }
            __builtin_amdgcn_s_setprio(0);

            // ---- softmax numerator (in place) ----
            const bool dodiag = (k0 + 63 > qbase);
            if (dodiag) {
                #pragma unroll
                for (int r = 0; r < 16; r++) {
                    const int km = (r & 3) + 8*(r >> 2) + 4*hi;
                    float v0 = s0[r] * SC_LOG2E;
                    float v1 = s1[r] * SC_LOG2E;
                    if (k0 + km      > qg) v0 = NEG_BIG;
                    if (k0 + 32 + km > qg) v1 = NEG_BIG;
                    const float p0 = __builtin_amdgcn_exp2f(v0);
                    const float p1 = __builtin_amdgcn_exp2f(v1);
                    s0[r] = p0; s1[r] = p1;
                    lsum += p0 + p1;
                }
            } else {
                #pragma unroll
                for (int r = 0; r < 16; r++) {
                    const float p0 = __builtin_amdgcn_exp2f(s0[r] * SC_LOG2E);
                    const float p1 = __builtin_amdgcn_exp2f(s1[r] * SC_LOG2E);
                    s0[r] = p0; s1[r] = p1;
                    lsum += p0 + p1;
                }
            }

            // ---- P fragments (cvt_pk + permlane32_swap) + PV ----
            __builtin_amdgcn_s_setprio(1);
            #pragma unroll
            for (int c = 0; c < 4; c++) {
                const int R = 8 * (c & 1);
                unsigned x0, x1, y0, y1;
                if (c < 2) {
                    x0 = cvt_pk_bf16(s0[R+0], s0[R+1]);
                    x1 = cvt_pk_bf16(s0[R+2], s0[R+3]);
                    y0 = cvt_pk_bf16(s0[R+4], s0[R+5]);
                    y1 = cvt_pk_bf16(s0[R+6], s0[R+7]);
                } else {
                    x0 = cvt_pk_bf16(s1[R+0], s1[R+1]);
                    x1 = cvt_pk_bf16(s1[R+2], s1[R+3]);
                    y0 = cvt_pk_bf16(s1[R+4], s1[R+5]);
                    y1 = cvt_pk_bf16(s1[R+6], s1[R+7]);
                }
                pl32_swap(x0, y0);
                pl32_swap(x1, y1);
                union { unsigned u[4]; short8 s8; } pf;
                pf.u[0] = x0; pf.u[1] = x1; pf.u[2] = y0; pf.u[3] = y1;
                short8 vf0 = *reinterpret_cast<const short8*>(&Vs[ln32     ][c*16 + hi*8]);
                short8 vf1 = *reinterpret_cast<const short8*>(&Vs[32 + ln32][c*16 + hi*8]);
                o0 = __builtin_amdgcn_mfma_f32_32x32x16_bf16(vf0, pf.s8, o0, 0, 0, 0);
                o1 = __builtin_amdgcn_mfma_f32_32x32x16_bf16(vf1, pf.s8, o1, 0, 0, 0);
            }
            __builtin_amdgcn_s_setprio(0);
        }

        // full row-sum: this lane + its hi/lo partner
        const float ls = lsum + __shfl_xor(lsum, 32, 64);
        const float rq = 1.0f / ls;

        // epilogue: O^T regs -> O[q][d], d = dt*32 + 8*g + 4*hi + (0..3)
        __hip_bfloat16* Orow = O + (((size_t)b_ * SL + qg) * NH + h) * DK;
        #pragma unroll
        for (int g = 0; g < 4; g++) {
            uint2 pk0, pk1;
            pk0.x = cvt_pk_bf16(o0[4*g+0]*rq, o0[4*g+1]*rq);
            pk0.y = cvt_pk_bf16(o0[4*g+2]*rq, o0[4*g+3]*rq);
            pk1.x = cvt_pk_bf16(o1[4*g+0]*rq, o1[4*g+1]*rq);
            pk1.y = cvt_pk_bf16(o1[4*g+2]*rq, o1[4*g+3]*rq);
            *reinterpret_cast<uint2*>(Orow + 8*g + 4*hi)      = pk0;
            *reinterpret_cast<uint2*>(Orow + 32 + 8*g + 4*hi) = pk1;
        }
    }
}

// ---------------------------------------------------------------------------
// ws layout (fast path, 72 MiB): [q 16M][k 16M][v 16M][xb 16M][wq 2M][wk 2M]
// [wv 2M][wo 2M]. Attention O reuses xb (dead after projections); Wo GEMM
// writes fp32 directly to d_out (no copy).
// ---------------------------------------------------------------------------
extern "C" void kernel_launch(void* const* d_in, const int* in_sizes, int n_in,
                              void* d_out, int out_size, void* d_ws, size_t ws_size,
                              hipStream_t stream)
{
    const float* x  = (const float*)d_in[0];
    const float* Wq = (const float*)d_in[1];
    const float* Wk = (const float*)d_in[2];
    const float* Wv = (const float*)d_in[3];
    const float* Wo = (const float*)d_in[4];

    __hip_bfloat16* q_ws = (__hip_bfloat16*)d_ws;
    __hip_bfloat16* k_ws = q_ws + QKV_ELEMS;
    __hip_bfloat16* v_ws = k_ws + QKV_ELEMS;

    const dim3 gb(256);
    const size_t FAST_WS = (3 * QKV_ELEMS + QKV_ELEMS + 4 * (size_t)DM * DM)
                           * sizeof(__hip_bfloat16);   // 72 MiB

    if (ws_size >= FAST_WS) {
        __hip_bfloat16* xb  = v_ws + QKV_ELEMS;
        __hip_bfloat16* wqb = xb  + QKV_ELEMS;        // [Wq;Wk;Wv] contiguous
        __hip_bfloat16* wob = wqb + 3 * (size_t)DM * DM;

        cvt_all<<<12288, 256, 0, stream>>>(x, Wq, Wk, Wv, Wo, xb);

        gemm_qkv<<<dim3(64, 24), gb, 0, stream>>>(xb, wqb, q_ws, k_ws, v_ws);

        attn_causal<<<dim3(8, BB*NH), 256, 0, stream>>>(q_ws, k_ws, v_ws, xb);

        gemm_wo<<<dim3(64, 8), gb, 0, stream>>>(xb, wob, (float*)d_out);
    } else {
        __hip_bfloat16* obuf = (__hip_bfloat16*)d_out;
        float*          fbuf = (float*)d_ws;
        const dim3 gg(64, 8);
        gemm_bt<false, 0><<<gg, gb, 0, stream>>>(x, Wq, q_ws);
        gemm_bt<false, 0><<<gg, gb, 0, stream>>>(x, Wk, k_ws);
        gemm_bt<false, 1><<<gg, gb, 0, stream>>>(x, Wv, v_ws);
        attn_causal<<<dim3(8, BB*NH), 256, 0, stream>>>(q_ws, k_ws, v_ws, obuf);
        gemm_bt<true, 2><<<gg, gb, 0, stream>>>(obuf, Wo, fbuf);
        (void)hipMemcpyAsync(d_out, fbuf, QKV_ELEMS * sizeof(float),
                             hipMemcpyDeviceToDevice, stream);
    }
}